// Round 6
// baseline (83.427 us; speedup 1.0000x reference)
//
#include <hip/hip_runtime.h>
#include <math.h>

// Problem constants (from reference)
#define SPIN 365
#define TRAINL 200000
#define ML 2.9086f
#define SLINV (1.0f / 1.898f)

#define THREADS 256              // 4 waves/block -> 2+ blocks/CU co-resident
#define ITEMS 2
#define CHUNK (THREADS * ITEMS)  // 512 elements/block
#define NW (THREADS / 64)        // 4 waves
// B = 262144 -> G = 512 blocks; 2/CU co-resident (low VGPR/LDS) — lookback safe.
// Carry scan supports G <= 512 (64 lanes x 8 entries).

typedef float v2f __attribute__((ext_vector_type(2)));
typedef float v4f __attribute__((ext_vector_type(4)));

struct Sc { float oo, oogw, ol1, b0, k; };

__device__ __forceinline__ Sc get_sc(const float* w0, const float* w1,
                                     const float* w2, const float* w3,
                                     const float* b0p, const float* wb2p) {
  float e_om = __expf(w0[0]);
  float e_gw = __expf(w1[0]);
  float e_lm = __expf(w2[0]);
  float e_fm = __expf(w3[0]);
  float denom = e_om + e_gw + e_lm + e_fm;
  Sc s;
  s.oo   = e_om / denom;
  s.oogw = e_gw / denom;
  s.ol1  = e_lm / denom;
  s.b0   = b0p[0];
  s.k    = wb2p[0] * SLINV;
  return s;
}

__device__ __forceinline__ float sigm_fast(float z) {
  return __fdividef(1.0f, 1.0f + __expf(-z));
}

__device__ __forceinline__ void nts2(float* p, float a, float b) {
  v2f v = { a, b };
  __builtin_nontemporal_store(v, (v2f*)p);
}
__device__ __forceinline__ void nts4(float* p, float a, float b, float c, float d) {
  v4f v = { a, b, c, d };
  __builtin_nontemporal_store(v, (v4f*)p);
}

// ws float layout:
// [0,G)   aggregate P   [G,2G)  aggregate Q
// [2G,3G) y partial sum [3G,4G) y partial sumsq
// [4G,5G) (as uint) publish flags — poison 0xAAAAAAAA = unset; 1u = set (no memset needed)

extern "C" __global__ __launch_bounds__(THREADS) void kf(
    const float* __restrict__ x, const float* __restrict__ y,
    const int* __restrict__ tlp,
    const float* __restrict__ w0, const float* __restrict__ w1,
    const float* __restrict__ w2, const float* __restrict__ w3,
    const float* __restrict__ b0p, const float* __restrict__ wb2p,
    float* __restrict__ out, float* __restrict__ ws,
    unsigned int* __restrict__ flags, int B, int G)
{
  const int g = blockIdx.x, tid = threadIdx.x;
  const int lane = tid & 63, wid = tid >> 6;
  const int tl = tlp[0];
  const Sc sc = get_sc(w0, w1, w2, w3, b0p, wb2p);
  const int base = g * CHUNK + tid * ITEMS;
  const bool full = (base + ITEMS) <= B;
  const int YB = min(G, (TRAINL + CHUNK - 1) / CHUNK);  // blocks holding y range (391)

  // ---- load x once ----
  float u1v[ITEMS], u2v[ITEMS];
  if (full) {
    float4 a = *(const float4*)(x + 2 * (size_t)base);
    u1v[0] = a.x; u2v[0] = a.y; u1v[1] = a.z; u2v[1] = a.w;
  } else {
    for (int j = 0; j < ITEMS; j++) {
      int p = base + j;
      u1v[j] = (p < B) ? x[2*(size_t)p]     : 0.f;
      u2v[j] = (p < B) ? x[2*(size_t)p + 1] : 0.f;
    }
  }

  float P = 1.f, Q = 0.f;
  float olv[ITEMS], fv[ITEMS];
  for (int j = 0; j < ITEMS; j++) {
    int p = base + j;
    float ol = sc.ol1 * sigm_fast(sc.b0 + (u2v[j] - ML) * sc.k);
    float f  = 1.0f - sc.oo - ol - sc.oogw;
    olv[j] = ol; fv[j] = f;
    bool act = (p >= tl) && (p < B);
    if (act) { Q = f * Q + u1v[j]; P *= f; }
  }

  // ---- wave-inclusive scan of own pairs ----
  float iP = P, iQ = Q;
  #pragma unroll
  for (int off = 1; off < 64; off <<= 1) {
    float pa = __shfl_up(iP, off);
    float pb = __shfl_up(iQ, off);
    if (lane >= off) { iQ = iP * pb + iQ; iP = iP * pa; }
  }

  // ---- y_obs partials ----
  float s = 0.f, ss = 0.f;
  if (full && base < TRAINL) {
    float2 yv = *(const float2*)(y + base);
    float vv[2] = { yv.x, yv.y };
    for (int j = 0; j < ITEMS; j++) {
      int p = base + j;
      if (p >= SPIN && p < TRAINL) { s += vv[j]; ss += vv[j]*vv[j]; }
    }
  } else {
    for (int j = 0; j < ITEMS; j++) {
      int p = base + j;
      if (p >= SPIN && p < TRAINL && p < B) { float v = y[p]; s += v; ss += v*v; }
    }
  }
  #pragma unroll
  for (int off = 1; off < 64; off <<= 1) {
    s  += __shfl_xor(s,  off);
    ss += __shfl_xor(ss, off);
  }

  __shared__ float wOA[NW], wOB[NW], rS[NW], rSS[NW];
  __shared__ float shCg, shS, shSS;
  if (lane == 63) { wOA[wid] = iP; wOB[wid] = iQ; }
  if (lane == 0)  { rS[wid] = s; rSS[wid] = ss; }
  __syncthreads();                                            // (1)

  // ---- publish: relaxed atomic payloads, vmcnt release, flag ----
  if (tid == 0) {
    float A = 1.f, Bq = 0.f, S = 0.f, SS = 0.f;
    #pragma unroll
    for (int w = 0; w < NW; w++) {
      Bq = wOA[w] * Bq + wOB[w];
      A  = wOA[w] * A;
      S += rS[w]; SS += rSS[w];
    }
    __hip_atomic_store(&ws[g],       A,  __ATOMIC_RELAXED, __HIP_MEMORY_SCOPE_AGENT);
    __hip_atomic_store(&ws[G + g],   Bq, __ATOMIC_RELAXED, __HIP_MEMORY_SCOPE_AGENT);
    __hip_atomic_store(&ws[2*G + g], S,  __ATOMIC_RELAXED, __HIP_MEMORY_SCOPE_AGENT);
    __hip_atomic_store(&ws[3*G + g], SS, __ATOMIC_RELAXED, __HIP_MEMORY_SCOPE_AGENT);
    asm volatile("s_waitcnt vmcnt(0)" ::: "memory");          // hand-rolled release
    __hip_atomic_store(&flags[g], 1u, __ATOMIC_RELAXED, __HIP_MEMORY_SCOPE_AGENT);
  }

  // ---- c-independent outputs (overlap other blocks' publishing); NT stores ----
  if (full) {
    bool a0 = (base >= tl), a1 = (base + 1 >= tl);
    nts2(out + 4*(size_t)B + base, 0.f, 0.f);                                    // bp_n
    nts2(out + 5*(size_t)B + base, 0.f, 0.f);                                    // gate_ib
    nts2(out + 6*(size_t)B + base, a0?sc.oo:0.f,   a1?sc.oo:0.f);                // gate_oo
    nts2(out + 7*(size_t)B + base, a0?sc.oogw:0.f, a1?sc.oogw:0.f);              // gate_oogw
    nts2(out + 8*(size_t)B + base, a0?olv[0]:0.f,  a1?olv[1]:0.f);               // gate_ol
    nts2(out + 9*(size_t)B + base, a0?fv[0]:0.f,   a1?fv[1]:0.f);                // gate_f
  } else {
    for (int j = 0; j < ITEMS; j++) {
      int p = base + j;
      if (p < B) {
        bool act = (p >= tl);
        out[4*(size_t)B+p] = 0.f;                  out[5*(size_t)B+p] = 0.f;
        out[6*(size_t)B+p] = act ? sc.oo   : 0.f;  out[7*(size_t)B+p] = act ? sc.oogw : 0.f;
        out[8*(size_t)B+p] = act ? olv[j]  : 0.f;  out[9*(size_t)B+p] = act ? fv[j]   : 0.f;
      }
    }
  }

  // ---- per-thread exclusive prefix within block ----
  float eP = __shfl_up(iP, 1);
  float eQ = __shfl_up(iQ, 1);
  if (lane == 0) { eP = 1.f; eQ = 0.f; }
  float OWA = 1.f, OWB = 0.f;
  for (int w = 0; w < wid; w++) { OWB = wOA[w] * OWB + wOB[w]; OWA *= wOA[w]; }
  const float Ae = eP * OWA;
  const float Be = eP * OWB + eQ;

  // ---- wave 0 polls flags [0, max(g, YB)); everyone else parks at barrier ----
  const int NEED = (g > YB) ? g : YB;
  if (wid == 0) {
    bool ok = false;
    while (!ok) {
      bool mine = true;
      for (int idx = lane; idx < NEED; idx += 64) {
        unsigned f = __hip_atomic_load(&flags[idx], __ATOMIC_RELAXED, __HIP_MEMORY_SCOPE_AGENT);
        mine &= (f == 1u);
      }
      ok = __all(mine);
      if (!ok) __builtin_amdgcn_s_sleep(2);
    }
  }
  __syncthreads();                                            // (2) data visible
  asm volatile("" ::: "memory");

  // ---- wave 0: carry via capture-lane serial compose (8 aggregates/lane) ----
  if (wid == 0) {
    float cA = 1.f, cB = 0.f;      // lane-local compose of its 8 aggregates
    float capA = 1.f, capB = 0.f;  // local prefix captured at global idx == g
    bool cap = false;
    #pragma unroll
    for (int k = 0; k < 8; k++) {
      int idx = lane * 8 + k;
      if (idx == g) { capA = cA; capB = cB; cap = true; }
      if (idx < G) {
        float aP = __hip_atomic_load(&ws[idx],     __ATOMIC_RELAXED, __HIP_MEMORY_SCOPE_AGENT);
        float aQ = __hip_atomic_load(&ws[G + idx], __ATOMIC_RELAXED, __HIP_MEMORY_SCOPE_AGENT);
        cB = aP * cB + aQ;   // compose: later(idx) after earlier(prefix)
        cA = aP * cA;
      }
    }
    // wave-inclusive scan of per-lane totals
    float jP = cA, jQ = cB;
    #pragma unroll
    for (int off = 1; off < 64; off <<= 1) {
      float pa = __shfl_up(jP, off);
      float pb = __shfl_up(jQ, off);
      if (lane >= off) { jQ = jP * pb + jQ; jP = jP * pa; }
    }
    // exclusive prefix Q for this lane
    float exQ = __shfl_up(jQ, 1);
    float exP = __shfl_up(jP, 1);
    if (lane == 0) { exQ = 0.f; exP = 1.f; }
    (void)exP;
    if (cap) shCg = capA * exQ + capB;   // exactly one lane captures (lane g>>3)
  }
  // ---- wave 1: y reduction over [0, YB) (same order every block) ----
  if (wid == 1) {
    float S = 0.f, SS = 0.f;
    #pragma unroll
    for (int k = 0; k < 8; k++) {
      int idx = lane * 8 + k;
      if (idx < YB) {
        S  += __hip_atomic_load(&ws[2*G + idx], __ATOMIC_RELAXED, __HIP_MEMORY_SCOPE_AGENT);
        SS += __hip_atomic_load(&ws[3*G + idx], __ATOMIC_RELAXED, __HIP_MEMORY_SCOPE_AGENT);
      }
    }
    #pragma unroll
    for (int off = 1; off < 64; off <<= 1) {
      S  += __shfl_xor(S,  off);
      SS += __shfl_xor(SS, off);
    }
    if (lane == 0) { shS = S; shSS = SS; }
  }
  __syncthreads();                                            // (3)

  float nY = (float)(TRAINL - SPIN);
  float mean = shS / nY;
  float var = (shSS - nY * mean * mean) / (nY - 1.0f);
  float ostd = sqrtf(fmaxf(var, 0.f));
  const float Cg = shCg;

  // ---- c-dependent outputs ----
  float c = Ae * Cg + Be;                 // c entering this thread's first element
  float vh[ITEMS], vc[ITEMS], vl[ITEMS], vgw[ITEMS], vos[ITEMS];
  for (int j = 0; j < ITEMS; j++) {
    int p = base + j;
    bool act = (p >= tl) && (p < B);
    float c0 = c;                         // scan emits c BEFORE this step
    vh[j]  = sc.oo * c0;
    vc[j]  = c0;
    vl[j]  = olv[j] * c0;
    vgw[j] = sc.oogw * c0;
    vos[j] = act ? ostd : 0.f;
    if (act) { c = fv[j] * c + u1v[j]; }
  }

  if (full) {
    nts2(out + (size_t)base,        vh[0],  vh[1]);    // h_n
    nts2(out + (size_t)B + base,    vc[0],  vc[1]);    // c_n
    nts2(out + 2*(size_t)B + base,  vl[0],  vl[1]);    // l_n
    nts2(out + 3*(size_t)B + base,  vgw[0], vgw[1]);   // gw_n
    nts2(out + 12*(size_t)B + base, vos[0], vos[1]);   // obs_std
    nts4(out + 10*(size_t)B + 2*(size_t)base, vh[0], vos[0], vh[1], vos[1]); // h_nout
  } else {
    for (int j = 0; j < ITEMS; j++) {
      int p = base + j;
      if (p < B) {
        out[(size_t)p]            = vh[j];
        out[(size_t)B + p]        = vc[j];
        out[2*(size_t)B + p]      = vl[j];
        out[3*(size_t)B + p]      = vgw[j];
        out[12*(size_t)B + p]     = vos[j];
        out[10*(size_t)B + 2*p]     = vh[j];
        out[10*(size_t)B + 2*p + 1] = vos[j];
      }
    }
  }
}

extern "C" void kernel_launch(void* const* d_in, const int* in_sizes, int n_in,
                              void* d_out, int out_size, void* d_ws, size_t ws_size,
                              hipStream_t stream) {
  const float* x   = (const float*)d_in[0];
  const float* y   = (const float*)d_in[1];
  // d_in[2] = epoch (unused)
  const int*   tl  = (const int*)d_in[3];
  const float* w0  = (const float*)d_in[4];  // weight_r_yom
  const float* w1  = (const float*)d_in[5];  // weight_r_yom_gw
  const float* w2  = (const float*)d_in[6];  // weight_r_ylm
  const float* w3  = (const float*)d_in[7];  // weight_r_yfm
  const float* b0  = (const float*)d_in[8];  // bias_b0_ylm
  const float* wb2 = (const float*)d_in[9];  // weight_b2_ylm

  float* out = (float*)d_out;
  float* ws  = (float*)d_ws;

  const int B = in_sizes[0] / 2;            // x is (B, 1, 2)
  const int G = (B + CHUNK - 1) / CHUNK;    // 512 for B=262144 (carry scan needs G<=512)

  unsigned int* flags = (unsigned int*)(ws + 4 * (size_t)G);
  // flags need no zeroing: harness poison 0xAAAAAAAA != 1u

  kf<<<G, THREADS, 0, stream>>>(x, y, tl, w0, w1, w2, w3, b0, wb2,
                                out, ws, flags, B, G);
}

// Round 7
// 81.681 us; speedup vs baseline: 1.0214x; 1.0214x over previous
//
#include <hip/hip_runtime.h>
#include <math.h>

// Problem constants (from reference)
#define SPIN 365
#define TRAINL 200000
#define ML 2.9086f
#define SLINV (1.0f / 1.898f)

#define THREADS 256              // 4 waves/block -> 2 blocks/CU
#define ITEMS 2
#define CHUNK (THREADS * ITEMS)  // 512 elements/block
#define NW (THREADS / 64)        // 4 waves
// B = 262144 -> G = 512 blocks. k2 carry scan supports G <= 2*THREADS = 512.

typedef float v2f __attribute__((ext_vector_type(2)));
typedef float v4f __attribute__((ext_vector_type(4)));

struct Sc { float oo, oogw, ol1, b0, k; };

__device__ __forceinline__ Sc get_sc(const float* w0, const float* w1,
                                     const float* w2, const float* w3,
                                     const float* b0p, const float* wb2p) {
  float e_om = __expf(w0[0]);
  float e_gw = __expf(w1[0]);
  float e_lm = __expf(w2[0]);
  float e_fm = __expf(w3[0]);
  float denom = e_om + e_gw + e_lm + e_fm;
  Sc s;
  s.oo   = e_om / denom;
  s.oogw = e_gw / denom;
  s.ol1  = e_lm / denom;
  s.b0   = b0p[0];
  s.k    = wb2p[0] * SLINV;
  return s;
}

__device__ __forceinline__ float sigm_fast(float z) {
  return __fdividef(1.0f, 1.0f + __expf(-z));
}

__device__ __forceinline__ void nts2(float* p, float a, float b) {
  v2f v = { a, b };
  __builtin_nontemporal_store(v, (v2f*)p);
}
__device__ __forceinline__ void nts4(float* p, float a, float b, float c, float d) {
  v4f v = { a, b, c, d };
  __builtin_nontemporal_store(v, (v4f*)p);
}

// ws float layout:
// [0,G)   aggregate P    [G,2G)  aggregate Q
// [2G,3G) y partial sum  [3G,4G) y partial sumsq

// ------------- k1: block aggregates + y partials + gate outputs (NT) -------------
extern "C" __global__ __launch_bounds__(THREADS) void k1(
    const float* __restrict__ x, const float* __restrict__ y,
    const int* __restrict__ tlp,
    const float* __restrict__ w0, const float* __restrict__ w1,
    const float* __restrict__ w2, const float* __restrict__ w3,
    const float* __restrict__ b0p, const float* __restrict__ wb2p,
    float* __restrict__ out, float* __restrict__ ws, int B, int G)
{
  const int g = blockIdx.x, tid = threadIdx.x;
  const int lane = tid & 63, wid = tid >> 6;
  const int tl = tlp[0];
  const Sc sc = get_sc(w0, w1, w2, w3, b0p, wb2p);
  const int base = g * CHUNK + tid * ITEMS;
  const bool full = (base + ITEMS) <= B;

  float u1v[ITEMS], u2v[ITEMS];
  if (full) {
    float4 a = *(const float4*)(x + 2 * (size_t)base);   // plain load: warm L2 for k2
    u1v[0] = a.x; u2v[0] = a.y; u1v[1] = a.z; u2v[1] = a.w;
  } else {
    for (int j = 0; j < ITEMS; j++) {
      int p = base + j;
      u1v[j] = (p < B) ? x[2*(size_t)p]     : 0.f;
      u2v[j] = (p < B) ? x[2*(size_t)p + 1] : 0.f;
    }
  }

  float P = 1.f, Q = 0.f;
  float olv[ITEMS], fv[ITEMS];
  for (int j = 0; j < ITEMS; j++) {
    int p = base + j;
    float ol = sc.ol1 * sigm_fast(sc.b0 + (u2v[j] - ML) * sc.k);
    float f  = 1.0f - sc.oo - ol - sc.oogw;
    olv[j] = ol; fv[j] = f;
    bool act = (p >= tl) && (p < B);
    if (act) { Q = f * Q + u1v[j]; P *= f; }
  }

  // gate outputs (NT: don't evict x from L2)
  if (full) {
    bool a0 = (base >= tl), a1 = (base + 1 >= tl);
    nts2(out + 4*(size_t)B + base, 0.f, 0.f);                         // bp_n
    nts2(out + 5*(size_t)B + base, 0.f, 0.f);                         // gate_ib
    nts2(out + 6*(size_t)B + base, a0?sc.oo:0.f,   a1?sc.oo:0.f);     // gate_oo
    nts2(out + 7*(size_t)B + base, a0?sc.oogw:0.f, a1?sc.oogw:0.f);   // gate_oogw
    nts2(out + 8*(size_t)B + base, a0?olv[0]:0.f,  a1?olv[1]:0.f);    // gate_ol
    nts2(out + 9*(size_t)B + base, a0?fv[0]:0.f,   a1?fv[1]:0.f);     // gate_f
  } else {
    for (int j = 0; j < ITEMS; j++) {
      int p = base + j;
      if (p < B) {
        bool act = (p >= tl);
        out[4*(size_t)B+p] = 0.f;                  out[5*(size_t)B+p] = 0.f;
        out[6*(size_t)B+p] = act ? sc.oo   : 0.f;  out[7*(size_t)B+p] = act ? sc.oogw : 0.f;
        out[8*(size_t)B+p] = act ? olv[j]  : 0.f;  out[9*(size_t)B+p] = act ? fv[j]   : 0.f;
      }
    }
  }

  // order-preserving wave reduce of affine pairs
  #pragma unroll
  for (int off = 1; off < 64; off <<= 1) {
    float pL = __shfl_down(P, off);
    float qL = __shfl_down(Q, off);
    Q = pL * Q + qL;
    P = pL * P;
  }

  // y partials
  float s = 0.f, ss = 0.f;
  if (full && base < TRAINL) {
    float2 yv = *(const float2*)(y + base);
    float vv[2] = { yv.x, yv.y };
    for (int j = 0; j < ITEMS; j++) {
      int p = base + j;
      if (p >= SPIN && p < TRAINL) { s += vv[j]; ss += vv[j]*vv[j]; }
    }
  } else {
    for (int j = 0; j < ITEMS; j++) {
      int p = base + j;
      if (p >= SPIN && p < TRAINL && p < B) { float v = y[p]; s += v; ss += v*v; }
    }
  }
  #pragma unroll
  for (int off = 1; off < 64; off <<= 1) {
    s  += __shfl_xor(s,  off);
    ss += __shfl_xor(ss, off);
  }

  __shared__ float wA[NW], wB[NW], rS[NW], rSS[NW];
  if (lane == 0) { wA[wid] = P; wB[wid] = Q; rS[wid] = s; rSS[wid] = ss; }
  __syncthreads();
  if (tid == 0) {
    float A = 1.f, Bq = 0.f, S = 0.f, SS = 0.f;
    #pragma unroll
    for (int w = 0; w < NW; w++) {
      Bq = wA[w] * Bq + wB[w];
      A  = wA[w] * A;
      S += rS[w]; SS += rSS[w];
    }
    ws[g] = A; ws[G + g] = Bq; ws[2*G + g] = S; ws[3*G + g] = SS;
  }
}

// ------------- k2: carry scan + std + c-dependent outputs (NT) --------------------
extern "C" __global__ __launch_bounds__(THREADS) void k2(
    const float* __restrict__ x, const int* __restrict__ tlp,
    const float* __restrict__ w0, const float* __restrict__ w1,
    const float* __restrict__ w2, const float* __restrict__ w3,
    const float* __restrict__ b0p, const float* __restrict__ wb2p,
    float* __restrict__ out, const float* __restrict__ ws, int B, int G)
{
  const int g = blockIdx.x, tid = threadIdx.x;
  const int lane = tid & 63, wid = tid >> 6;
  const int tl = tlp[0];
  const int YB = min(G, (TRAINL + CHUNK - 1) / CHUNK);   // 391
  const Sc sc = get_sc(w0, w1, w2, w3, b0p, wb2p);
  const int base = g * CHUNK + tid * ITEMS;
  const bool full = (base + ITEMS) <= B;

  // issue dependency loads first: 2 aggregates + 2 y-partials per thread
  const int i0 = 2 * tid, i1 = 2 * tid + 1;
  float aP0 = (i0 < G) ? ws[i0]     : 1.f;
  float aQ0 = (i0 < G) ? ws[G + i0] : 0.f;
  float aP1 = (i1 < G) ? ws[i1]     : 1.f;
  float aQ1 = (i1 < G) ? ws[G + i1] : 0.f;
  float yS  = ((tid)       < YB) ? ws[2*G + tid]       : 0.f;
  float ySS = ((tid)       < YB) ? ws[3*G + tid]       : 0.f;
  if (tid + THREADS < YB) { yS += ws[2*G + THREADS + tid]; ySS += ws[3*G + THREADS + tid]; }

  // own elements (L2-warm from k1)
  float u1v[ITEMS], u2v[ITEMS];
  if (full) {
    float4 a = *(const float4*)(x + 2 * (size_t)base);
    u1v[0] = a.x; u2v[0] = a.y; u1v[1] = a.z; u2v[1] = a.w;
  } else {
    for (int j = 0; j < ITEMS; j++) {
      int p = base + j;
      u1v[j] = (p < B) ? x[2*(size_t)p]     : 0.f;
      u2v[j] = (p < B) ? x[2*(size_t)p + 1] : 0.f;
    }
  }
  float P = 1.f, Q = 0.f;
  float olv[ITEMS], fv[ITEMS];
  for (int j = 0; j < ITEMS; j++) {
    int p = base + j;
    float ol = sc.ol1 * sigm_fast(sc.b0 + (u2v[j] - ML) * sc.k);
    float f  = 1.0f - sc.oo - ol - sc.oogw;
    olv[j] = ol; fv[j] = f;
    bool act = (p >= tl) && (p < B);
    if (act) { Q = f * Q + u1v[j]; P *= f; }
  }

  // wave-inclusive scan of own pairs
  float iP = P, iQ = Q;
  #pragma unroll
  for (int off = 1; off < 64; off <<= 1) {
    float pa = __shfl_up(iP, off);
    float pb = __shfl_up(iQ, off);
    if (lane >= off) { iQ = iP * pb + iQ; iP = iP * pa; }
  }

  // thread-composite of the two aggregates, wave-inclusive scan
  float cP = aP1 * aP0;
  float cQ = aP1 * aQ0 + aQ1;
  float jP = cP, jQ = cQ;
  #pragma unroll
  for (int off = 1; off < 64; off <<= 1) {
    float pa = __shfl_up(jP, off);
    float pb = __shfl_up(jQ, off);
    if (lane >= off) { jQ = jP * pb + jQ; jP = jP * pa; }
  }

  // y butterfly (identical order in every block)
  #pragma unroll
  for (int off = 1; off < 64; off <<= 1) {
    yS  += __shfl_xor(yS,  off);
    ySS += __shfl_xor(ySS, off);
  }

  __shared__ float wOA[NW], wOB[NW];   // own-scan wave aggregates
  __shared__ float wAA[NW], wAB[NW];   // aggregate-scan wave aggregates
  __shared__ float rS[NW], rSS[NW];
  __shared__ float sQ[2 * THREADS];    // inclusive aggregate-scan Q per block index
  if (lane == 63) { wOA[wid] = iP; wOB[wid] = iQ; wAA[wid] = jP; wAB[wid] = jQ; }
  if (lane == 0)  { rS[wid] = yS; rSS[wid] = ySS; }
  __syncthreads();

  // cross-wave exclusive prefixes (serial over 4 LDS entries)
  float OWA = 1.f, OWB = 0.f, AWA = 1.f, AWB = 0.f;
  for (int w = 0; w < wid; w++) {
    OWB = wOA[w] * OWB + wOB[w];  OWA *= wOA[w];
    AWB = wAA[w] * AWB + wAB[w];  AWA *= wAA[w];
  }

  // thread-exclusive prefix within block for aggregate scan
  float pe = __shfl_up(jP, 1);
  float qe = __shfl_up(jQ, 1);
  if (lane == 0) { pe = 1.f; qe = 0.f; }
  float EQ = pe * AWB + qe;            // exclusive Q before index 2*tid
  // inclusive Q at 2*tid and 2*tid+1
  float incQ0 = aP0 * EQ + aQ0;
  float incQ1 = aP1 * incQ0 + aQ1;
  sQ[i0] = incQ0;
  if (i1 < 2 * THREADS) sQ[i1] = incQ1;

  // obsstd (deterministic identical order)
  float S = 0.f, SS = 0.f;
  #pragma unroll
  for (int w = 0; w < NW; w++) { S += rS[w]; SS += rSS[w]; }
  float nY = (float)(TRAINL - SPIN);
  float mean = S / nY;
  float var = (SS - nY * mean * mean) / (nY - 1.0f);
  float ostd = sqrtf(fmaxf(var, 0.f));
  __syncthreads();

  const float Cg = (g == 0) ? 0.f : sQ[g - 1];   // carry into this block (c0 = 0)

  // thread-exclusive prefix within block for OWN scan
  float eP = __shfl_up(iP, 1);
  float eQ = __shfl_up(iQ, 1);
  if (lane == 0) { eP = 1.f; eQ = 0.f; }
  const float Ae = eP * OWA;
  const float Be = eP * OWB + eQ;

  float c = Ae * Cg + Be;              // c entering this thread's first element
  float vh[ITEMS], vc[ITEMS], vl[ITEMS], vgw[ITEMS], vos[ITEMS];
  for (int j = 0; j < ITEMS; j++) {
    int p = base + j;
    bool act = (p >= tl) && (p < B);
    float c0 = c;                      // scan emits c BEFORE this step
    vh[j]  = sc.oo * c0;
    vc[j]  = c0;
    vl[j]  = olv[j] * c0;
    vgw[j] = sc.oogw * c0;
    vos[j] = act ? ostd : 0.f;
    if (act) { c = fv[j] * c + u1v[j]; }
  }

  if (full) {
    nts2(out + (size_t)base,        vh[0],  vh[1]);    // h_n
    nts2(out + (size_t)B + base,    vc[0],  vc[1]);    // c_n
    nts2(out + 2*(size_t)B + base,  vl[0],  vl[1]);    // l_n
    nts2(out + 3*(size_t)B + base,  vgw[0], vgw[1]);   // gw_n
    nts2(out + 12*(size_t)B + base, vos[0], vos[1]);   // obs_std
    nts4(out + 10*(size_t)B + 2*(size_t)base, vh[0], vos[0], vh[1], vos[1]); // h_nout
  } else {
    for (int j = 0; j < ITEMS; j++) {
      int p = base + j;
      if (p < B) {
        out[(size_t)p]            = vh[j];
        out[(size_t)B + p]        = vc[j];
        out[2*(size_t)B + p]      = vl[j];
        out[3*(size_t)B + p]      = vgw[j];
        out[12*(size_t)B + p]     = vos[j];
        out[10*(size_t)B + 2*p]     = vh[j];
        out[10*(size_t)B + 2*p + 1] = vos[j];
      }
    }
  }
}

extern "C" void kernel_launch(void* const* d_in, const int* in_sizes, int n_in,
                              void* d_out, int out_size, void* d_ws, size_t ws_size,
                              hipStream_t stream) {
  const float* x   = (const float*)d_in[0];
  const float* y   = (const float*)d_in[1];
  // d_in[2] = epoch (unused)
  const int*   tl  = (const int*)d_in[3];
  const float* w0  = (const float*)d_in[4];  // weight_r_yom
  const float* w1  = (const float*)d_in[5];  // weight_r_yom_gw
  const float* w2  = (const float*)d_in[6];  // weight_r_ylm
  const float* w3  = (const float*)d_in[7];  // weight_r_yfm
  const float* b0  = (const float*)d_in[8];  // bias_b0_ylm
  const float* wb2 = (const float*)d_in[9];  // weight_b2_ylm

  float* out = (float*)d_out;
  float* ws  = (float*)d_ws;

  const int B = in_sizes[0] / 2;            // x is (B, 1, 2)
  const int G = (B + CHUNK - 1) / CHUNK;    // 512 for B=262144 (k2 needs G <= 512)

  k1<<<G, THREADS, 0, stream>>>(x, y, tl, w0, w1, w2, w3, b0, wb2, out, ws, B, G);
  k2<<<G, THREADS, 0, stream>>>(x, tl, w0, w1, w2, w3, b0, wb2, out, ws, B, G);
}

// Round 8
// 80.921 us; speedup vs baseline: 1.0310x; 1.0094x over previous
//
#include <hip/hip_runtime.h>
#include <math.h>

// Problem constants (from reference)
#define SPIN 365
#define TRAINL 200000
#define ML 2.9086f
#define SLINV (1.0f / 1.898f)

#define THREADS 512              // 8 waves/block (R4-best shape)
#define ITEMS 2
#define CHUNK (THREADS * ITEMS)  // 1024 elements/block
#define NW (THREADS / 64)        // 8 waves
// B = 262144 -> G = 256 blocks. k2 aggregate scan assumes G <= 256 (waves 0-3).

typedef float v2f __attribute__((ext_vector_type(2)));
typedef float v4f __attribute__((ext_vector_type(4)));

struct Sc { float oo, oogw, ol1, b0, k; };

__device__ __forceinline__ Sc get_sc(const float* w0, const float* w1,
                                     const float* w2, const float* w3,
                                     const float* b0p, const float* wb2p) {
  float e_om = __expf(w0[0]);
  float e_gw = __expf(w1[0]);
  float e_lm = __expf(w2[0]);
  float e_fm = __expf(w3[0]);
  float denom = e_om + e_gw + e_lm + e_fm;
  Sc s;
  s.oo   = e_om / denom;
  s.oogw = e_gw / denom;
  s.ol1  = e_lm / denom;
  s.b0   = b0p[0];
  s.k    = wb2p[0] * SLINV;
  return s;
}

__device__ __forceinline__ float sigm_fast(float z) {
  return __fdividef(1.0f, 1.0f + __expf(-z));
}

__device__ __forceinline__ void nts2(float* p, float a, float b) {
  v2f v = { a, b };
  __builtin_nontemporal_store(v, (v2f*)p);
}
__device__ __forceinline__ void nts4(float* p, float a, float b, float c, float d) {
  v4f v = { a, b, c, d };
  __builtin_nontemporal_store(v, (v4f*)p);
}

// ws float layout (G = 256):
// [0,G)   aggregate P    [G,2G)  aggregate Q
// [2G,3G) y partial sum  [3G,4G) y partial sumsq

// ------------- k1: block aggregates + y partials + gate outputs (NT) -------------
extern "C" __global__ __launch_bounds__(THREADS) void k1(
    const float* __restrict__ x, const float* __restrict__ y,
    const int* __restrict__ tlp,
    const float* __restrict__ w0, const float* __restrict__ w1,
    const float* __restrict__ w2, const float* __restrict__ w3,
    const float* __restrict__ b0p, const float* __restrict__ wb2p,
    float* __restrict__ out, float* __restrict__ ws, int B, int G)
{
  const int g = blockIdx.x, tid = threadIdx.x;
  const int lane = tid & 63, wid = tid >> 6;
  const int tl = tlp[0];
  const Sc sc = get_sc(w0, w1, w2, w3, b0p, wb2p);
  const int base = g * CHUNK + tid * ITEMS;
  const bool full = (base + ITEMS) <= B;

  float u1v[ITEMS], u2v[ITEMS];
  if (full) {
    float4 a = *(const float4*)(x + 2 * (size_t)base);   // plain: warm L2 for k2
    u1v[0] = a.x; u2v[0] = a.y; u1v[1] = a.z; u2v[1] = a.w;
  } else {
    for (int j = 0; j < ITEMS; j++) {
      int p = base + j;
      u1v[j] = (p < B) ? x[2*(size_t)p]     : 0.f;
      u2v[j] = (p < B) ? x[2*(size_t)p + 1] : 0.f;
    }
  }

  float P = 1.f, Q = 0.f;
  float olv[ITEMS], fv[ITEMS];
  for (int j = 0; j < ITEMS; j++) {
    int p = base + j;
    float ol = sc.ol1 * sigm_fast(sc.b0 + (u2v[j] - ML) * sc.k);
    float f  = 1.0f - sc.oo - ol - sc.oogw;
    olv[j] = ol; fv[j] = f;
    bool act = (p >= tl) && (p < B);
    if (act) { Q = f * Q + u1v[j]; P *= f; }
  }

  // gate outputs (NT: keep x resident in L2)
  if (full) {
    bool a0 = (base >= tl), a1 = (base + 1 >= tl);
    nts2(out + 4*(size_t)B + base, 0.f, 0.f);                         // bp_n
    nts2(out + 5*(size_t)B + base, 0.f, 0.f);                         // gate_ib
    nts2(out + 6*(size_t)B + base, a0?sc.oo:0.f,   a1?sc.oo:0.f);     // gate_oo
    nts2(out + 7*(size_t)B + base, a0?sc.oogw:0.f, a1?sc.oogw:0.f);   // gate_oogw
    nts2(out + 8*(size_t)B + base, a0?olv[0]:0.f,  a1?olv[1]:0.f);    // gate_ol
    nts2(out + 9*(size_t)B + base, a0?fv[0]:0.f,   a1?fv[1]:0.f);     // gate_f
  } else {
    for (int j = 0; j < ITEMS; j++) {
      int p = base + j;
      if (p < B) {
        bool act = (p >= tl);
        out[4*(size_t)B+p] = 0.f;                  out[5*(size_t)B+p] = 0.f;
        out[6*(size_t)B+p] = act ? sc.oo   : 0.f;  out[7*(size_t)B+p] = act ? sc.oogw : 0.f;
        out[8*(size_t)B+p] = act ? olv[j]  : 0.f;  out[9*(size_t)B+p] = act ? fv[j]   : 0.f;
      }
    }
  }

  // order-preserving wave reduce of affine pairs
  #pragma unroll
  for (int off = 1; off < 64; off <<= 1) {
    float pL = __shfl_down(P, off);
    float qL = __shfl_down(Q, off);
    Q = pL * Q + qL;
    P = pL * P;
  }

  // y partials (NT load: y is read exactly once in the whole pipeline)
  float s = 0.f, ss = 0.f;
  if (full && base < TRAINL) {
    v2f yv = __builtin_nontemporal_load((const v2f*)(y + base));
    float vv[2] = { yv.x, yv.y };
    for (int j = 0; j < ITEMS; j++) {
      int p = base + j;
      if (p >= SPIN && p < TRAINL) { s += vv[j]; ss += vv[j]*vv[j]; }
    }
  } else {
    for (int j = 0; j < ITEMS; j++) {
      int p = base + j;
      if (p >= SPIN && p < TRAINL && p < B) { float v = y[p]; s += v; ss += v*v; }
    }
  }
  #pragma unroll
  for (int off = 1; off < 64; off <<= 1) {
    s  += __shfl_xor(s,  off);
    ss += __shfl_xor(ss, off);
  }

  __shared__ float wA[NW], wB[NW], rS[NW], rSS[NW];
  if (lane == 0) { wA[wid] = P; wB[wid] = Q; rS[wid] = s; rSS[wid] = ss; }
  __syncthreads();
  if (tid == 0) {
    float A = 1.f, Bq = 0.f, S = 0.f, SS = 0.f;
    #pragma unroll
    for (int w = 0; w < NW; w++) {
      Bq = wA[w] * Bq + wB[w];
      A  = wA[w] * A;
      S += rS[w]; SS += rSS[w];
    }
    ws[g] = A; ws[G + g] = Bq; ws[2*G + g] = S; ws[3*G + g] = SS;
  }
}

// ------------- k2: wave-split carry scan (waves 0-3) + y-std (waves 4-7) ---------
extern "C" __global__ __launch_bounds__(THREADS) void k2(
    const float* __restrict__ x, const int* __restrict__ tlp,
    const float* __restrict__ w0, const float* __restrict__ w1,
    const float* __restrict__ w2, const float* __restrict__ w3,
    const float* __restrict__ b0p, const float* __restrict__ wb2p,
    float* __restrict__ out, const float* __restrict__ ws, int B, int G)
{
  const int g = blockIdx.x, tid = threadIdx.x;
  const int lane = tid & 63, wid = tid >> 6;
  const int tl = tlp[0];
  const int YB = min(G, (TRAINL + CHUNK - 1) / CHUNK);   // 196
  const Sc sc = get_sc(w0, w1, w2, w3, b0p, wb2p);
  const int base = g * CHUNK + tid * ITEMS;
  const bool full = (base + ITEMS) <= B;

  // issue dependency loads first
  float aP = 1.f, aQ = 0.f, yS = 0.f, ySS = 0.f;
  if (tid < G) {                       // waves 0-3: aggregates
    aP = ws[tid];
    aQ = ws[G + tid];
  } else {                             // waves 4-7: y partials
    int k = tid - G;                   // k in [0, 256)
    if (k < YB) { yS = ws[2*G + k]; ySS = ws[3*G + k]; }
  }

  // own elements (L2-warm from k1)
  float u1v[ITEMS], u2v[ITEMS];
  if (full) {
    float4 a = *(const float4*)(x + 2 * (size_t)base);
    u1v[0] = a.x; u2v[0] = a.y; u1v[1] = a.z; u2v[1] = a.w;
  } else {
    for (int j = 0; j < ITEMS; j++) {
      int p = base + j;
      u1v[j] = (p < B) ? x[2*(size_t)p]     : 0.f;
      u2v[j] = (p < B) ? x[2*(size_t)p + 1] : 0.f;
    }
  }
  float P = 1.f, Q = 0.f;
  float olv[ITEMS], fv[ITEMS];
  for (int j = 0; j < ITEMS; j++) {
    int p = base + j;
    float ol = sc.ol1 * sigm_fast(sc.b0 + (u2v[j] - ML) * sc.k);
    float f  = 1.0f - sc.oo - ol - sc.oogw;
    olv[j] = ol; fv[j] = f;
    bool act = (p >= tl) && (p < B);
    if (act) { Q = f * Q + u1v[j]; P *= f; }
  }

  // wave-inclusive scan of own pairs (all 8 waves)
  float iP = P, iQ = Q;
  #pragma unroll
  for (int off = 1; off < 64; off <<= 1) {
    float pa = __shfl_up(iP, off);
    float pb = __shfl_up(iQ, off);
    if (lane >= off) { iQ = iP * pb + iQ; iP = iP * pa; }
  }

  // waves 0-3: wave-inclusive scan of aggregates
  float jP = aP, jQ = aQ;
  #pragma unroll
  for (int off = 1; off < 64; off <<= 1) {
    float pa = __shfl_up(jP, off);
    float pb = __shfl_up(jQ, off);
    if (lane >= off) { jQ = jP * pb + jQ; jP = jP * pa; }
  }
  // waves 4-7: y butterfly within wave
  #pragma unroll
  for (int off = 1; off < 64; off <<= 1) {
    yS  += __shfl_xor(yS,  off);
    ySS += __shfl_xor(ySS, off);
  }

  __shared__ float wOA[NW], wOB[NW];   // own-scan wave aggregates (8)
  __shared__ float wAA[4], wAB[4];     // aggregate-scan wave aggregates (waves 0-3)
  __shared__ float rS[4], rSS[4];      // y wave sums (waves 4-7)
  __shared__ float sQ[256];            // inclusive aggregate-scan Q (G <= 256)
  if (lane == 63) {
    wOA[wid] = iP; wOB[wid] = iQ;
    if (wid < 4) { wAA[wid] = jP; wAB[wid] = jQ; }
  }
  if (lane == 0 && wid >= 4) { rS[wid - 4] = yS; rSS[wid - 4] = ySS; }
  __syncthreads();                                           // (1)

  // own cross-wave exclusive prefix (all threads; serial over <=7 entries)
  float OWA = 1.f, OWB = 0.f;
  for (int w = 0; w < wid; w++) { OWB = wOA[w] * OWB + wOB[w]; OWA *= wOA[w]; }

  // waves 0-3: publish inclusive aggregate-scan Q
  if (tid < G) {
    float AWB = 0.f, AWA = 1.f;
    for (int w = 0; w < wid; w++) { AWB = wAA[w] * AWB + wAB[w]; AWA *= wAA[w]; }
    sQ[tid] = jP * AWB + jQ;
  }

  // everyone: deterministic y total from 4 wave sums
  float S = rS[0] + rS[1] + rS[2] + rS[3];
  float SS = rSS[0] + rSS[1] + rSS[2] + rSS[3];
  float nY = (float)(TRAINL - SPIN);
  float mean = S / nY;
  float var = (SS - nY * mean * mean) / (nY - 1.0f);
  float ostd = sqrtf(fmaxf(var, 0.f));
  __syncthreads();                                           // (2)

  const float Cg = (g == 0) ? 0.f : sQ[g - 1];   // carry into this block (c0 = 0)

  // thread-exclusive prefix within block for own scan
  float eP = __shfl_up(iP, 1);
  float eQ = __shfl_up(iQ, 1);
  if (lane == 0) { eP = 1.f; eQ = 0.f; }
  const float Ae = eP * OWA;
  const float Be = eP * OWB + eQ;

  float c = Ae * Cg + Be;              // c entering this thread's first element
  float vh[ITEMS], vc[ITEMS], vl[ITEMS], vgw[ITEMS], vos[ITEMS];
  for (int j = 0; j < ITEMS; j++) {
    int p = base + j;
    bool act = (p >= tl) && (p < B);
    float c0 = c;                      // scan emits c BEFORE this step
    vh[j]  = sc.oo * c0;
    vc[j]  = c0;
    vl[j]  = olv[j] * c0;
    vgw[j] = sc.oogw * c0;
    vos[j] = act ? ostd : 0.f;
    if (act) { c = fv[j] * c + u1v[j]; }
  }

  if (full) {
    nts2(out + (size_t)base,        vh[0],  vh[1]);    // h_n
    nts2(out + (size_t)B + base,    vc[0],  vc[1]);    // c_n
    nts2(out + 2*(size_t)B + base,  vl[0],  vl[1]);    // l_n
    nts2(out + 3*(size_t)B + base,  vgw[0], vgw[1]);   // gw_n
    nts2(out + 12*(size_t)B + base, vos[0], vos[1]);   // obs_std
    nts4(out + 10*(size_t)B + 2*(size_t)base, vh[0], vos[0], vh[1], vos[1]); // h_nout
  } else {
    for (int j = 0; j < ITEMS; j++) {
      int p = base + j;
      if (p < B) {
        out[(size_t)p]            = vh[j];
        out[(size_t)B + p]        = vc[j];
        out[2*(size_t)B + p]      = vl[j];
        out[3*(size_t)B + p]      = vgw[j];
        out[12*(size_t)B + p]     = vos[j];
        out[10*(size_t)B + 2*p]     = vh[j];
        out[10*(size_t)B + 2*p + 1] = vos[j];
      }
    }
  }
}

extern "C" void kernel_launch(void* const* d_in, const int* in_sizes, int n_in,
                              void* d_out, int out_size, void* d_ws, size_t ws_size,
                              hipStream_t stream) {
  const float* x   = (const float*)d_in[0];
  const float* y   = (const float*)d_in[1];
  // d_in[2] = epoch (unused)
  const int*   tl  = (const int*)d_in[3];
  const float* w0  = (const float*)d_in[4];  // weight_r_yom
  const float* w1  = (const float*)d_in[5];  // weight_r_yom_gw
  const float* w2  = (const float*)d_in[6];  // weight_r_ylm
  const float* w3  = (const float*)d_in[7];  // weight_r_yfm
  const float* b0  = (const float*)d_in[8];  // bias_b0_ylm
  const float* wb2 = (const float*)d_in[9];  // weight_b2_ylm

  float* out = (float*)d_out;
  float* ws  = (float*)d_ws;

  const int B = in_sizes[0] / 2;            // x is (B, 1, 2)
  const int G = (B + CHUNK - 1) / CHUNK;    // 256 for B=262144 (k2 needs G <= 256)

  k1<<<G, THREADS, 0, stream>>>(x, y, tl, w0, w1, w2, w3, b0, wb2, out, ws, B, G);
  k2<<<G, THREADS, 0, stream>>>(x, tl, w0, w1, w2, w3, b0, wb2, out, ws, B, G);
}